// Round 1
// baseline (344.005 us; speedup 1.0000x reference)
//
#include <hip/hip_runtime.h>
#include <hip/hip_cooperative_groups.h>

namespace cg = cooperative_groups;

#define NB        16
#define DD        512
#define HW2       512        // float2 groups per (n,d) plane (1024 floats / 2)
#define RSEG      16         // outputs (along D) per work item
#define SCOPE     63
#define HALF      31
#define MAXSTEPS  20
#define NELEMD    8388608.0  // 16*512*32*32
#define NBLOCKS   512
#define NTHREADS  256

// ws layout (floats): [0, 2^23)  = state buffer B0
//                     [2^23,2^24)= inhib buffer
//                     byte 2^26  = 21 doubles of diff accumulators
__global__ __launch_bounds__(NTHREADS, 2)
void rin_kernel(const float* __restrict__ act,
                const float* __restrict__ w_in,
                const float* __restrict__ w_rec,
                float* __restrict__ outp,
                float* __restrict__ wsp)
{
    cg::grid_group grid = cg::this_grid();

    const int tid = blockIdx.x * NTHREADS + threadIdx.x;
    const int g   = tid & (HW2 - 1);      // float2 column within plane (coalesced across lanes)
    const int u   = tid >> 9;             // 0..255
    const int n   = u & (NB - 1);
    const int seg = u >> 4;               // 0..15 (second item adds 256 to d0)
    const int d0base = seg * RSEG;

    const float2* act2 = (const float2*)act;
    float2* b0   = (float2*)wsp;                      // even-step buffer (state0 here)
    float2* b1   = (float2*)outp;                     // odd-step buffer == output
    float2* inhib = (float2*)(wsp + (1UL << 23));
    double* dacc  = (double*)(wsp + (1UL << 24));

    const int colbase = (n * DD) * HW2 + g;           // float2 index of (n, d=0, g)

    if (tid == 0) {
        for (int s = 0; s <= MAXSTEPS; ++s) dacc[s] = 0.0;
    }

    int T = MAXSTEPS;

    for (int s = 0; s <= MAXSTEPS; ++s) {
        const float2* src = (s == 0) ? act2 : ((s & 1) ? b0 : b1);
        float2*       dst = (s == 0) ? b0   : ((s & 1) ? b1 : b0);
        const float*  wp  = (s == 0) ? w_in : w_rec;

        double lsum = 0.0;

        #pragma unroll 1
        for (int h = 0; h < 2; ++h) {
            const int d0 = d0base + h * 256;

            float2 accv[RSEG];
            float2 st[RSEG];
            #pragma unroll
            for (int r = 0; r < RSEG; ++r) accv[r] = make_float2(0.f, 0.f);

            // streaming register FIR: inputs i = d0-31 .. d0+15+31
            #pragma unroll
            for (int j = -HALF; j <= RSEG - 1 + HALF; ++j) {
                const int i = d0 + j;
                float2 x = make_float2(0.f, 0.f);
                if (i >= 0 && i < DD) x = src[colbase + i * HW2];
                if (j >= 0 && j < RSEG) st[j] = x;   // center states for the update
                #pragma unroll
                for (int r = 0; r < RSEG; ++r) {
                    const int k = j - r + HALF;      // tap index, compile-time
                    if (k >= 0 && k < SCOPE) {
                        const float wk = wp[k];      // uniform -> scalar load
                        accv[r].x += wk * x.x;
                        accv[r].y += wk * x.y;
                    }
                }
            }

            if (s == 0) {
                #pragma unroll
                for (int r = 0; r < RSEG; ++r) {
                    const int idx = colbase + (d0 + r) * HW2;
                    inhib[idx] = accv[r];            // inhib_in
                    dst[idx]   = accv[r];            // state0 = inhib_in
                }
            } else {
                #pragma unroll
                for (int r = 0; r < RSEG; ++r) {
                    const int idx = colbase + (d0 + r) * HW2;
                    const float2 ih = inhib[idx];
                    const float2 sv = st[r];
                    float2 phi, cand, dd;
                    phi.x  = (ih.x + accv[r].x) * 0.5f;
                    phi.y  = (ih.y + accv[r].y) * 0.5f;
                    cand.x = 0.95f * sv.x + 0.05f * phi.x;
                    cand.y = 0.95f * sv.y + 0.05f * phi.y;
                    dd.x = cand.x - sv.x;
                    dd.y = cand.y - sv.y;
                    lsum += (double)(dd.x * dd.x) + (double)(dd.y * dd.y);
                    dst[idx] = cand;
                }
            }
        }

        if (s > 0) {
            // block-level reduction of squared-diff sum, then one double atomic per block
            #pragma unroll
            for (int off = 32; off > 0; off >>= 1)
                lsum += __shfl_down(lsum, off, 64);
            __shared__ double wsum[NTHREADS / 64];
            const int lane = threadIdx.x & 63;
            const int wid  = threadIdx.x >> 6;
            if (lane == 0) wsum[wid] = lsum;
            __syncthreads();
            if (threadIdx.x == 0) {
                const double bs = wsum[0] + wsum[1] + wsum[2] + wsum[3];
                atomicAdd(&dacc[s], bs);
            }
        }

        grid.sync();

        if (s > 0) {
            const double tot = __hip_atomic_load(&dacc[s], __ATOMIC_RELAXED,
                                                 __HIP_MEMORY_SCOPE_AGENT);
            // reference: done |= (mean diff <= 0.001); frozen steps are no-ops -> break
            if ((float)(tot / NELEMD) <= 0.001f) { T = s; break; }
        }
    }

    // final state lives in the buffer written by step T: odd T -> b1 (already d_out)
    if (!(T & 1)) {
        #pragma unroll 1
        for (int h = 0; h < 2; ++h) {
            const int d0 = d0base + h * 256;
            #pragma unroll
            for (int r = 0; r < RSEG; ++r) {
                const int idx = colbase + (d0 + r) * HW2;
                b1[idx] = b0[idx];
            }
        }
    }
}

extern "C" void kernel_launch(void* const* d_in, const int* in_sizes, int n_in,
                              void* d_out, int out_size, void* d_ws, size_t ws_size,
                              hipStream_t stream) {
    const float* act   = (const float*)d_in[0];
    const float* w_in  = (const float*)d_in[1];
    const float* w_rec = (const float*)d_in[2];
    float* outp = (float*)d_out;
    float* wsp  = (float*)d_ws;

    void* args[] = { (void*)&act, (void*)&w_in, (void*)&w_rec,
                     (void*)&outp, (void*)&wsp };
    hipLaunchCooperativeKernel((void*)rin_kernel,
                               dim3(NBLOCKS), dim3(NTHREADS),
                               args, 0, stream);
}

// Round 6
// 210.620 us; speedup vs baseline: 1.6333x; 1.6333x over previous
//
#include <hip/hip_runtime.h>

#define DD       512        // channels (conv axis)
#define Q4       256        // float4 per (n,d) row
#define DSEG     16         // rows per thread
#define HALO     31
#define NWIN     78         // DSEG + 2*HALO
#define WZN      93         // padded taps: m = j - r + 15, j<78, r<16
#define SCOPE    63
#define MAXSTEPS 20
#define NELEMD   8388608.0  // 16*512*32*32
#define NSLOT    8
#define NTHREADS 256
#define NBLOCKS  512        // 16 n * 32 chunks

__device__ __forceinline__ unsigned short f2bf(float f) {
    unsigned int b = __float_as_uint(f);
    b += 0x7FFFu + ((b >> 16) & 1u);      // round-to-nearest-even
    return (unsigned short)(b >> 16);
}
__device__ __forceinline__ float bf2f(unsigned short u) {
    return __uint_as_float(((unsigned int)u) << 16);
}

// ---------- builder: padded weights, accumulator init, done flag ----------
__global__ void build_kernel(const float* __restrict__ w_in,
                             const float* __restrict__ w_rec,
                             float* __restrict__ wzin,
                             float* __restrict__ wzrec,
                             double* __restrict__ dacc,
                             int* __restrict__ done)
{
    const int t = threadIdx.x;
    if (t < WZN) {
        const int k = t - (DSEG - 1);             // tap index; valid iff 0<=k<63
        const bool v = (k >= 0 && k < SCOPE);
        wzin[t]  = v ? w_in[k]  : 0.f;
        wzrec[t] = v ? w_rec[k] : 0.f;
    }
    if (t < (MAXSTEPS + 1) * NSLOT)
        dacc[t * 8] = (t < NSLOT) ? 1e30 : 0.0;   // s==0 reads as "not converged"
    if (t == 0) *done = 0;
}

// ---------- 63-tap FIR over a 16-row segment, straight-line loads ----------
__device__ __forceinline__ void fir16(const float4* __restrict__ src,
                                      const float* __restrict__ wz,
                                      const int rowbase, const int d0, const int q,
                                      float4* __restrict__ acc)
{
    #pragma unroll
    for (int r = 0; r < DSEG; ++r) acc[r] = make_float4(0.f, 0.f, 0.f, 0.f);
    #pragma unroll 6
    for (int j = 0; j < NWIN; ++j) {
        const int d   = d0 + j - HALO;                       // block-uniform
        const int dcl = min(max(d, 0), DD - 1);              // clamp (scalar)
        float4 x = src[((rowbase + dcl) << 8) + q];          // always in-bounds
        if ((unsigned)d >= DD) x = make_float4(0.f, 0.f, 0.f, 0.f); // uniform
        #pragma unroll
        for (int r = 0; r < DSEG; ++r) {
            const float wk = wz[j - r + (DSEG - 1)];         // uniform s_load; 0-padded
            acc[r].x = fmaf(wk, x.x, acc[r].x);
            acc[r].y = fmaf(wk, x.y, acc[r].y);
            acc[r].z = fmaf(wk, x.z, acc[r].z);
            acc[r].w = fmaf(wk, x.w, acc[r].w);
        }
    }
}

__device__ __forceinline__ void decode_block(int bid, int& rowbase, int& d0) {
    const int nb = (bid & 7) * (NBLOCKS / 8) + (bid >> 3);   // XCD swizzle: 2 images/XCD
    rowbase = (nb >> 5) * DD;
    d0      = (nb & 31) * DSEG;
}

// ---------- step 0: inhib = conv(act, w_in); state0 = inhib ----------
__global__ __launch_bounds__(NTHREADS, 2)
void step0_kernel(const float4* __restrict__ act,
                  float4* __restrict__ b0,
                  ushort4* __restrict__ ib,
                  const float* __restrict__ wzin)
{
    int rowbase, d0; decode_block(blockIdx.x, rowbase, d0);
    const int q = threadIdx.x;

    float4 acc[DSEG];
    fir16(act, wzin, rowbase, d0, q, acc);
    #pragma unroll
    for (int r = 0; r < DSEG; ++r) {
        const int idx = ((rowbase + d0 + r) << 8) + q;
        b0[idx] = acc[r];
        ushort4 u;
        u.x = f2bf(acc[r].x); u.y = f2bf(acc[r].y);
        u.z = f2bf(acc[r].z); u.w = f2bf(acc[r].w);
        ib[idx] = u;
    }
}

// ---------- one fixed-point step (skips itself once converged) ----------
__global__ __launch_bounds__(NTHREADS, 2)
void step_kernel(const float4* __restrict__ src,
                 float4* __restrict__ dst,
                 const ushort4* __restrict__ ib,
                 const float* __restrict__ wzrec,
                 double* __restrict__ dacc,
                 int* __restrict__ done,
                 const int s)
{
    // sticky skip (set during an earlier step kernel; coherent at kernel boundary)
    if (__hip_atomic_load(done, __ATOMIC_RELAXED, __HIP_MEMORY_SCOPE_AGENT)) return;

    // convergence decision from step s-1's completed reduction
    double prev = 0.0;
    #pragma unroll
    for (int sl = 0; sl < NSLOT; ++sl)
        prev += dacc[((s - 1) * NSLOT + sl) * 8];
    if ((float)(prev / NELEMD) <= 0.001f) {       // uniform across whole grid
        if (threadIdx.x == 0)
            __hip_atomic_store(done, 1, __ATOMIC_RELAXED, __HIP_MEMORY_SCOPE_AGENT);
        return;
    }

    int rowbase, d0; decode_block(blockIdx.x, rowbase, d0);
    const int q = threadIdx.x;

    float4 acc[DSEG];
    fir16(src, wzrec, rowbase, d0, q, acc);       // rec = conv(state, w_rec)

    double lsum = 0.0;
    #pragma unroll
    for (int r = 0; r < DSEG; ++r) {
        const int idx = ((rowbase + d0 + r) << 8) + q;
        const float4  sv = src[idx];              // L1/L2-hot re-read of own row
        const ushort4 u  = ib[idx];
        float4 c;
        c.x = 0.95f * sv.x + 0.05f * ((bf2f(u.x) + acc[r].x) * 0.5f);
        c.y = 0.95f * sv.y + 0.05f * ((bf2f(u.y) + acc[r].y) * 0.5f);
        c.z = 0.95f * sv.z + 0.05f * ((bf2f(u.z) + acc[r].z) * 0.5f);
        c.w = 0.95f * sv.w + 0.05f * ((bf2f(u.w) + acc[r].w) * 0.5f);
        const float dx = c.x - sv.x, dy = c.y - sv.y;
        const float dz = c.z - sv.z, dw = c.w - sv.w;
        lsum += (double)(dx * dx) + (double)(dy * dy)
              + (double)(dz * dz) + (double)(dw * dw);
        dst[idx] = c;
    }

    // block reduction -> one double atomic per block (slot = XCD id)
    #pragma unroll
    for (int off = 32; off > 0; off >>= 1)
        lsum += __shfl_down(lsum, off, 64);
    __shared__ double wred[NTHREADS / 64];
    if ((threadIdx.x & 63) == 0) wred[threadIdx.x >> 6] = lsum;
    __syncthreads();
    if (threadIdx.x == 0)
        atomicAdd(&dacc[(s * NSLOT + (blockIdx.x & 7)) * 8],
                  wred[0] + wred[1] + wred[2] + wred[3]);
}

// ---------- final: if T even, state lives in b0 -> copy to out ----------
__global__ __launch_bounds__(NTHREADS, 2)
void final_kernel(const float4* __restrict__ b0,
                  float4* __restrict__ out,
                  const double* __restrict__ dacc)
{
    int T = MAXSTEPS;
    for (int t = 1; t <= MAXSTEPS; ++t) {
        double v = 0.0;
        #pragma unroll
        for (int sl = 0; sl < NSLOT; ++sl) v += dacc[(t * NSLOT + sl) * 8];
        if ((float)(v / NELEMD) <= 0.001f) { T = t; break; }
    }
    if (T & 1) return;                            // odd T: out (=b1) already final

    int rowbase, d0; decode_block(blockIdx.x, rowbase, d0);
    const int q = threadIdx.x;
    #pragma unroll
    for (int r = 0; r < DSEG; ++r) {
        const int idx = ((rowbase + d0 + r) << 8) + q;
        out[idx] = b0[idx];
    }
}

extern "C" void kernel_launch(void* const* d_in, const int* in_sizes, int n_in,
                              void* d_out, int out_size, void* d_ws, size_t ws_size,
                              hipStream_t stream) {
    const float* act   = (const float*)d_in[0];
    const float* w_in  = (const float*)d_in[1];
    const float* w_rec = (const float*)d_in[2];

    char* ws = (char*)d_ws;
    float4*  b0    = (float4*)ws;                           // 32 MiB state (even parity)
    ushort4* ib    = (ushort4*)(ws + (40u << 20));          // bf16 inhib (16.8 MB)
    double*  dacc  = (double*)(ws + (60u << 20));           // [21][8] slots, stride 8
    float*   wzin  = (float*)(ws + (60u << 20) + (16u << 10));
    float*   wzrec = wzin + 128;
    int*     done  = (int*)(wzrec + 128);
    float4*  b1    = (float4*)d_out;                        // odd-parity state == output

    build_kernel<<<1, NTHREADS, 0, stream>>>(w_in, w_rec, wzin, wzrec, dacc, done);
    step0_kernel<<<NBLOCKS, NTHREADS, 0, stream>>>((const float4*)act, b0, ib, wzin);
    for (int s = 1; s <= MAXSTEPS; ++s) {
        const float4* src = (s & 1) ? (const float4*)b0 : (const float4*)b1;
        float4*       dst = (s & 1) ? b1 : b0;
        step_kernel<<<NBLOCKS, NTHREADS, 0, stream>>>(src, dst, ib, wzrec, dacc, done, s);
    }
    final_kernel<<<NBLOCKS, NTHREADS, 0, stream>>>(b0, b1, dacc);
}

// Round 7
// 189.007 us; speedup vs baseline: 1.8201x; 1.1143x over previous
//
#include <hip/hip_runtime.h>

#define DD       512        // channels (conv axis)
#define Q4       256        // float4 per (n,d) row
#define DSEG     8          // rows per thread
#define HALO     31
#define NWIN     70         // DSEG + 2*HALO
#define WZN      77         // padded taps: m = j - r + (DSEG-1), j<70, r<8
#define SCOPE    63
#define MAXSTEPS 20
#define NELEMD   8388608.0  // 16*512*32*32
#define NSLOT    8
#define NTHREADS 256
#define NBLOCKS  1024       // 16 n * 64 chunks of 8 rows -> 4 blocks/CU

__device__ __forceinline__ unsigned short f2bf(float f) {
    unsigned int b = __float_as_uint(f);
    b += 0x7FFFu + ((b >> 16) & 1u);      // round-to-nearest-even
    return (unsigned short)(b >> 16);
}
__device__ __forceinline__ float bf2f(unsigned short u) {
    return __uint_as_float(((unsigned int)u) << 16);
}

// ---------- builder: padded weights, accumulator init, done flag ----------
__global__ void build_kernel(const float* __restrict__ w_in,
                             const float* __restrict__ w_rec,
                             float* __restrict__ wzin,
                             float* __restrict__ wzrec,
                             double* __restrict__ dacc,
                             int* __restrict__ done)
{
    const int t = threadIdx.x;
    if (t < WZN) {
        const int k = t - (DSEG - 1);             // tap index; valid iff 0<=k<63
        const bool v = (k >= 0 && k < SCOPE);
        wzin[t]  = v ? w_in[k]  : 0.f;
        wzrec[t] = v ? w_rec[k] : 0.f;
    }
    if (t < (MAXSTEPS + 1) * NSLOT)
        dacc[t * 8] = (t < NSLOT) ? 1e30 : 0.0;   // s==0 reads as "not converged"
    if (t == 0) *done = 0;
}

// ---------- 63-tap FIR over an 8-row segment, straight-line loads ----------
__device__ __forceinline__ void fir8(const float4* __restrict__ src,
                                     const float* __restrict__ wz,
                                     const int rowbase, const int d0, const int q,
                                     float4* __restrict__ acc)
{
    #pragma unroll
    for (int r = 0; r < DSEG; ++r) acc[r] = make_float4(0.f, 0.f, 0.f, 0.f);
    #pragma unroll 7
    for (int j = 0; j < NWIN; ++j) {
        const int d   = d0 + j - HALO;                       // block-uniform
        const int dcl = min(max(d, 0), DD - 1);              // clamp (scalar)
        float4 x = src[((rowbase + dcl) << 8) + q];          // always in-bounds
        if ((unsigned)d >= DD) x = make_float4(0.f, 0.f, 0.f, 0.f); // uniform
        #pragma unroll
        for (int r = 0; r < DSEG; ++r) {
            const float wk = wz[j - r + (DSEG - 1)];         // uniform s_load; 0-padded
            acc[r].x = fmaf(wk, x.x, acc[r].x);
            acc[r].y = fmaf(wk, x.y, acc[r].y);
            acc[r].z = fmaf(wk, x.z, acc[r].z);
            acc[r].w = fmaf(wk, x.w, acc[r].w);
        }
    }
}

__device__ __forceinline__ void decode_block(int bid, int& rowbase, int& d0) {
    const int nb = (bid & 7) * (NBLOCKS / 8) + (bid >> 3);   // XCD swizzle: 2 images/XCD
    rowbase = (nb >> 6) * DD;
    d0      = (nb & 63) * DSEG;
}

// ---------- step 0: inhib = conv(act, w_in); state0 = inhib ----------
__global__ __launch_bounds__(NTHREADS, 2)
void step0_kernel(const float4* __restrict__ act,
                  float4* __restrict__ b0,
                  ushort4* __restrict__ ib,
                  const float* __restrict__ wzin)
{
    int rowbase, d0; decode_block(blockIdx.x, rowbase, d0);
    const int q = threadIdx.x;

    float4 acc[DSEG];
    fir8(act, wzin, rowbase, d0, q, acc);
    #pragma unroll
    for (int r = 0; r < DSEG; ++r) {
        const int idx = ((rowbase + d0 + r) << 8) + q;
        b0[idx] = acc[r];
        ushort4 u;
        u.x = f2bf(acc[r].x); u.y = f2bf(acc[r].y);
        u.z = f2bf(acc[r].z); u.w = f2bf(acc[r].w);
        ib[idx] = u;
    }
}

// ---------- one fixed-point step (skips itself once converged) ----------
__global__ __launch_bounds__(NTHREADS, 2)
void step_kernel(const float4* __restrict__ src,
                 float4* __restrict__ dst,
                 const ushort4* __restrict__ ib,
                 const float* __restrict__ wzrec,
                 double* __restrict__ dacc,
                 int* __restrict__ done,
                 const int s)
{
    // sticky skip (set during an earlier step kernel; coherent at kernel boundary)
    if (__hip_atomic_load(done, __ATOMIC_RELAXED, __HIP_MEMORY_SCOPE_AGENT)) return;

    // convergence decision from step s-1's completed reduction
    double prev = 0.0;
    #pragma unroll
    for (int sl = 0; sl < NSLOT; ++sl)
        prev += dacc[((s - 1) * NSLOT + sl) * 8];
    if ((float)(prev / NELEMD) <= 0.001f) {       // uniform across whole grid
        if (threadIdx.x == 0)
            __hip_atomic_store(done, 1, __ATOMIC_RELAXED, __HIP_MEMORY_SCOPE_AGENT);
        return;
    }

    int rowbase, d0; decode_block(blockIdx.x, rowbase, d0);
    const int q = threadIdx.x;

    float4 acc[DSEG];
    fir8(src, wzrec, rowbase, d0, q, acc);        // rec = conv(state, w_rec)

    double lsum = 0.0;
    #pragma unroll
    for (int r = 0; r < DSEG; ++r) {
        const int idx = ((rowbase + d0 + r) << 8) + q;
        const float4  sv = src[idx];              // L1-hot re-read of own row
        const ushort4 u  = ib[idx];
        float4 c;
        c.x = 0.95f * sv.x + 0.05f * ((bf2f(u.x) + acc[r].x) * 0.5f);
        c.y = 0.95f * sv.y + 0.05f * ((bf2f(u.y) + acc[r].y) * 0.5f);
        c.z = 0.95f * sv.z + 0.05f * ((bf2f(u.z) + acc[r].z) * 0.5f);
        c.w = 0.95f * sv.w + 0.05f * ((bf2f(u.w) + acc[r].w) * 0.5f);
        const float dx = c.x - sv.x, dy = c.y - sv.y;
        const float dz = c.z - sv.z, dw = c.w - sv.w;
        lsum += (double)(dx * dx) + (double)(dy * dy)
              + (double)(dz * dz) + (double)(dw * dw);
        dst[idx] = c;
    }

    // block reduction -> one double atomic per block (slot = XCD id)
    #pragma unroll
    for (int off = 32; off > 0; off >>= 1)
        lsum += __shfl_down(lsum, off, 64);
    __shared__ double wred[NTHREADS / 64];
    if ((threadIdx.x & 63) == 0) wred[threadIdx.x >> 6] = lsum;
    __syncthreads();
    if (threadIdx.x == 0)
        atomicAdd(&dacc[(s * NSLOT + (blockIdx.x & 7)) * 8],
                  wred[0] + wred[1] + wred[2] + wred[3]);
}

// ---------- final: if T even, state lives in b0 -> copy to out ----------
__global__ __launch_bounds__(NTHREADS, 2)
void final_kernel(const float4* __restrict__ b0,
                  float4* __restrict__ out,
                  const double* __restrict__ dacc)
{
    int T = MAXSTEPS;
    for (int t = 1; t <= MAXSTEPS; ++t) {
        double v = 0.0;
        #pragma unroll
        for (int sl = 0; sl < NSLOT; ++sl) v += dacc[(t * NSLOT + sl) * 8];
        if ((float)(v / NELEMD) <= 0.001f) { T = t; break; }
    }
    if (T & 1) return;                            // odd T: out (=b1) already final

    int rowbase, d0; decode_block(blockIdx.x, rowbase, d0);
    const int q = threadIdx.x;
    #pragma unroll
    for (int r = 0; r < DSEG; ++r) {
        const int idx = ((rowbase + d0 + r) << 8) + q;
        out[idx] = b0[idx];
    }
}

extern "C" void kernel_launch(void* const* d_in, const int* in_sizes, int n_in,
                              void* d_out, int out_size, void* d_ws, size_t ws_size,
                              hipStream_t stream) {
    const float* act   = (const float*)d_in[0];
    const float* w_in  = (const float*)d_in[1];
    const float* w_rec = (const float*)d_in[2];

    char* ws = (char*)d_ws;
    float4*  b0    = (float4*)ws;                           // 33.6 MB state (even parity)
    ushort4* ib    = (ushort4*)(ws + (40u << 20));          // bf16 inhib (16.8 MB)
    double*  dacc  = (double*)(ws + (60u << 20));           // [21][8] slots, stride 8
    float*   wzin  = (float*)(ws + (60u << 20) + (16u << 10));
    float*   wzrec = wzin + 128;
    int*     done  = (int*)(wzrec + 128);
    float4*  b1    = (float4*)d_out;                        // odd-parity state == output

    build_kernel<<<1, NTHREADS, 0, stream>>>(w_in, w_rec, wzin, wzrec, dacc, done);
    step0_kernel<<<NBLOCKS, NTHREADS, 0, stream>>>((const float4*)act, b0, ib, wzin);
    for (int s = 1; s <= MAXSTEPS; ++s) {
        const float4* src = (s & 1) ? (const float4*)b0 : (const float4*)b1;
        float4*       dst = (s & 1) ? b1 : b0;
        step_kernel<<<NBLOCKS, NTHREADS, 0, stream>>>(src, dst, ib, wzrec, dacc, done, s);
    }
    final_kernel<<<NBLOCKS, NTHREADS, 0, stream>>>(b0, b1, dacc);
}

// Round 8
// 178.382 us; speedup vs baseline: 1.9285x; 1.0596x over previous
//
#include <hip/hip_runtime.h>

#define DD       512        // channels (conv axis)
#define Q4       256        // float4 per (n,d) row
#define DSEG     4          // rows per thread
#define ROWB     64         // rows per block
#define COLB     32         // float4 columns per block
#define HALO     31
#define WROWS    126        // ROWB + 2*HALO staged in LDS
#define NWIN     66         // DSEG + 2*HALO (per-thread window)
#define WZN      69         // padded taps: m = j - r + (DSEG-1), j<66, r<4
#define SCOPE    63
#define MAXSTEPS 20
#define NELEMD   8388608.0  // 16*512*32*32
#define NSLOT    8
#define NTHREADS 512        // 32 cols x 16 row-groups, 4 rows/thread
#define NBLOCKS  1024       // 16 n * 8 row-blocks * 8 col-tiles

__device__ __forceinline__ unsigned short f2bf(float f) {
    unsigned int b = __float_as_uint(f);
    b += 0x7FFFu + ((b >> 16) & 1u);      // round-to-nearest-even
    return (unsigned short)(b >> 16);
}
__device__ __forceinline__ float bf2f(unsigned short u) {
    return __uint_as_float(((unsigned int)u) << 16);
}

// ---------- builder: padded weights, accumulator init, done flag ----------
__global__ void build_kernel(const float* __restrict__ w_in,
                             const float* __restrict__ w_rec,
                             float* __restrict__ wzin,
                             float* __restrict__ wzrec,
                             double* __restrict__ dacc,
                             int* __restrict__ done)
{
    const int t = threadIdx.x;
    if (t < WZN) {
        const int k = t - (DSEG - 1);             // tap index; valid iff 0<=k<63
        const bool v = (k >= 0 && k < SCOPE);
        wzin[t]  = v ? w_in[k]  : 0.f;
        wzrec[t] = v ? w_rec[k] : 0.f;
    }
    if (t < (MAXSTEPS + 1) * NSLOT)
        dacc[t * 8] = (t < NSLOT) ? 1e30 : 0.0;   // s==0 reads as "not converged"
    if (t == 0) *done = 0;
}

// bid -> (rowbase, d0, colg): XCD swizzle keeps 2 whole images per XCD
__device__ __forceinline__ void decode_block(int bid, int& rowbase, int& d0, int& colg) {
    const int nb = (bid & 7) * (NBLOCKS / 8) + (bid >> 3);
    rowbase = (nb >> 6) * DD;                     // image * 512
    d0      = ((nb >> 3) & 7) * ROWB;             // row-block
    colg    = (nb & 7) * COLB;                    // col-tile (float4 units)
}

// ---------- stage the 126-row window slice into LDS ----------
__device__ __forceinline__ void stage(const float4* __restrict__ src,
                                      float4 (*S)[COLB],
                                      const int rowbase, const int d0, const int colg)
{
    const int c = threadIdx.x & (COLB - 1);
    const int g = threadIdx.x >> 5;               // [0,16)
    #pragma unroll
    for (int k = 0; k < 8; ++k) {
        const int wrow = g + 16 * k;
        if (wrow < WROWS) {
            const int d = d0 - HALO + wrow;
            float4 v = make_float4(0.f, 0.f, 0.f, 0.f);
            if ((unsigned)d < DD)
                v = src[(rowbase + d) * Q4 + colg + c];
            S[wrow][c] = v;
        }
    }
}

// ---------- 63-tap FIR over this thread's 4 rows, inputs from LDS ----------
__device__ __forceinline__ void fir4(const float4 (*S)[COLB],
                                     const float* __restrict__ wz,
                                     float4* __restrict__ acc)
{
    const int c = threadIdx.x & (COLB - 1);
    const int g = threadIdx.x >> 5;
    const int l0 = 4 * g;                         // LDS row of window start
    #pragma unroll
    for (int r = 0; r < DSEG; ++r) acc[r] = make_float4(0.f, 0.f, 0.f, 0.f);
    #pragma unroll 6
    for (int j = 0; j < NWIN; ++j) {
        const float4 x = S[l0 + j][c];
        #pragma unroll
        for (int r = 0; r < DSEG; ++r) {
            const float wk = wz[j - r + (DSEG - 1)];   // uniform s_load; 0-padded
            acc[r].x = fmaf(wk, x.x, acc[r].x);
            acc[r].y = fmaf(wk, x.y, acc[r].y);
            acc[r].z = fmaf(wk, x.z, acc[r].z);
            acc[r].w = fmaf(wk, x.w, acc[r].w);
        }
    }
}

// ---------- step 0: inhib = conv(act, w_in); state0 = inhib ----------
__global__ __launch_bounds__(NTHREADS, 2)
void step0_kernel(const float4* __restrict__ act,
                  float4* __restrict__ b0,
                  ushort4* __restrict__ ib,
                  const float* __restrict__ wzin)
{
    __shared__ float4 S[WROWS][COLB];             // 63 KB
    int rowbase, d0, colg; decode_block(blockIdx.x, rowbase, d0, colg);
    const int c = threadIdx.x & (COLB - 1);
    const int g = threadIdx.x >> 5;

    stage(act, S, rowbase, d0, colg);
    __syncthreads();

    float4 acc[DSEG];
    fir4(S, wzin, acc);

    #pragma unroll
    for (int r = 0; r < DSEG; ++r) {
        const int idx = (rowbase + d0 + 4 * g + r) * Q4 + colg + c;
        b0[idx] = acc[r];
        ushort4 u;
        u.x = f2bf(acc[r].x); u.y = f2bf(acc[r].y);
        u.z = f2bf(acc[r].z); u.w = f2bf(acc[r].w);
        ib[idx] = u;
    }
}

// ---------- one fixed-point step (skips itself once converged) ----------
__global__ __launch_bounds__(NTHREADS, 2)
void step_kernel(const float4* __restrict__ src,
                 float4* __restrict__ dst,
                 const ushort4* __restrict__ ib,
                 const float* __restrict__ wzrec,
                 double* __restrict__ dacc,
                 int* __restrict__ done,
                 const int s)
{
    // sticky skip (set during an earlier step kernel; coherent at kernel boundary)
    if (__hip_atomic_load(done, __ATOMIC_RELAXED, __HIP_MEMORY_SCOPE_AGENT)) return;

    // convergence decision from step s-1's completed reduction
    double prev = 0.0;
    #pragma unroll
    for (int sl = 0; sl < NSLOT; ++sl)
        prev += dacc[((s - 1) * NSLOT + sl) * 8];
    if ((float)(prev / NELEMD) <= 0.001f) {       // uniform across whole grid
        if (threadIdx.x == 0)
            __hip_atomic_store(done, 1, __ATOMIC_RELAXED, __HIP_MEMORY_SCOPE_AGENT);
        return;
    }

    __shared__ float4 S[WROWS][COLB];             // 63 KB
    int rowbase, d0, colg; decode_block(blockIdx.x, rowbase, d0, colg);
    const int c = threadIdx.x & (COLB - 1);
    const int g = threadIdx.x >> 5;

    stage(src, S, rowbase, d0, colg);
    __syncthreads();

    float4 acc[DSEG];
    fir4(S, wzrec, acc);                          // rec = conv(state, w_rec)

    double lsum = 0.0;
    #pragma unroll
    for (int r = 0; r < DSEG; ++r) {
        const int row = d0 + 4 * g + r;
        const int idx = (rowbase + row) * Q4 + colg + c;
        const float4  sv = S[4 * g + HALO + r][c];     // old state from LDS
        const ushort4 u  = ib[idx];
        float4 cv;
        cv.x = 0.95f * sv.x + 0.05f * ((bf2f(u.x) + acc[r].x) * 0.5f);
        cv.y = 0.95f * sv.y + 0.05f * ((bf2f(u.y) + acc[r].y) * 0.5f);
        cv.z = 0.95f * sv.z + 0.05f * ((bf2f(u.z) + acc[r].z) * 0.5f);
        cv.w = 0.95f * sv.w + 0.05f * ((bf2f(u.w) + acc[r].w) * 0.5f);
        const float dx = cv.x - sv.x, dy = cv.y - sv.y;
        const float dz = cv.z - sv.z, dw = cv.w - sv.w;
        lsum += (double)(dx * dx) + (double)(dy * dy)
              + (double)(dz * dz) + (double)(dw * dw);
        dst[idx] = cv;
    }

    // block reduction -> one double atomic per block (slot = XCD id)
    #pragma unroll
    for (int off = 32; off > 0; off >>= 1)
        lsum += __shfl_down(lsum, off, 64);
    __shared__ double wred[NTHREADS / 64];
    if ((threadIdx.x & 63) == 0) wred[threadIdx.x >> 6] = lsum;
    __syncthreads();
    if (threadIdx.x == 0) {
        double bs = 0.0;
        #pragma unroll
        for (int q = 0; q < NTHREADS / 64; ++q) bs += wred[q];
        atomicAdd(&dacc[(s * NSLOT + (blockIdx.x & 7)) * 8], bs);
    }
}

// ---------- final: if T even, state lives in b0 -> copy to out ----------
__global__ __launch_bounds__(NTHREADS, 2)
void final_kernel(const float4* __restrict__ b0,
                  float4* __restrict__ out,
                  const double* __restrict__ dacc)
{
    int T = MAXSTEPS;
    for (int t = 1; t <= MAXSTEPS; ++t) {
        double v = 0.0;
        #pragma unroll
        for (int sl = 0; sl < NSLOT; ++sl) v += dacc[(t * NSLOT + sl) * 8];
        if ((float)(v / NELEMD) <= 0.001f) { T = t; break; }
    }
    if (T & 1) return;                            // odd T: out (=b1) already final

    const int gid = blockIdx.x * NTHREADS + threadIdx.x;   // 524288 threads
    #pragma unroll
    for (int r = 0; r < 4; ++r) {
        const int idx = gid + r * (NBLOCKS * NTHREADS);    // 2M float4 total
        out[idx] = b0[idx];
    }
}

extern "C" void kernel_launch(void* const* d_in, const int* in_sizes, int n_in,
                              void* d_out, int out_size, void* d_ws, size_t ws_size,
                              hipStream_t stream) {
    const float* act   = (const float*)d_in[0];
    const float* w_in  = (const float*)d_in[1];
    const float* w_rec = (const float*)d_in[2];

    char* ws = (char*)d_ws;
    float4*  b0    = (float4*)ws;                           // 33.6 MB state (even parity)
    ushort4* ib    = (ushort4*)(ws + (40u << 20));          // bf16 inhib (16.8 MB)
    double*  dacc  = (double*)(ws + (60u << 20));           // [21][8] slots, stride 8
    float*   wzin  = (float*)(ws + (60u << 20) + (16u << 10));
    float*   wzrec = wzin + 128;
    int*     done  = (int*)(wzrec + 128);
    float4*  b1    = (float4*)d_out;                        // odd-parity state == output

    build_kernel<<<1, 256, 0, stream>>>(w_in, w_rec, wzin, wzrec, dacc, done);
    step0_kernel<<<NBLOCKS, NTHREADS, 0, stream>>>((const float4*)act, b0, ib, wzin);
    for (int s = 1; s <= MAXSTEPS; ++s) {
        const float4* src = (s & 1) ? (const float4*)b0 : (const float4*)b1;
        float4*       dst = (s & 1) ? b1 : b0;
        step_kernel<<<NBLOCKS, NTHREADS, 0, stream>>>(src, dst, ib, wzrec, dacc, done, s);
    }
    final_kernel<<<NBLOCKS, NTHREADS, 0, stream>>>(b0, b1, dacc);
}